// Round 4
// baseline (921.450 us; speedup 1.0000x reference)
//
#include <hip/hip_runtime.h>
#include <math.h>

#define S 512
#define DIN 256
#define H 512

// native vector type for nontemporal 16B stores (HIP float4 is a class and
// is rejected by __builtin_nontemporal_store)
typedef float f4 __attribute__((ext_vector_type(4)));

// ---------------------------------------------------------------------------
// Kernel 1: stable rank sort of 512 timestamps (matches jnp.argsort stable).
// One block, 512 threads. O(S^2) compares via LDS.
// ---------------------------------------------------------------------------
__global__ __launch_bounds__(512) void sort_kernel(
    const float* __restrict__ ts, const float* __restrict__ amp,
    int* __restrict__ order, float* __restrict__ ts_s, float* __restrict__ amp_s)
{
    __shared__ float sts[S];
    int i = threadIdx.x;
    sts[i] = ts[i];
    __syncthreads();
    float ti = sts[i];
    int rank = 0;
    for (int j = 0; j < S; ++j) {
        float tj = sts[j];
        rank += (tj < ti) || (tj == ti && j < i);
    }
    order[rank] = i;
    ts_s[rank]  = ti;
    amp_s[rank] = amp[i];
}

// Block-wide mean/rsqrt(var+eps) over 512 values held as 2 per thread (256 thr).
__device__ __forceinline__ void block_stats_512(float s, float ss, float* red,
                                                float& mean, float& inv)
{
    for (int off = 32; off > 0; off >>= 1) {
        s  += __shfl_down(s, off);
        ss += __shfl_down(ss, off);
    }
    int wid = threadIdx.x >> 6;
    if ((threadIdx.x & 63) == 0) { red[wid] = s; red[4 + wid] = ss; }
    __syncthreads();
    if (threadIdx.x == 0) {
        float Sm  = red[0] + red[1] + red[2] + red[3];
        float SSm = red[4] + red[5] + red[6] + red[7];
        float m = Sm * (1.0f / 512.0f);
        float v = SSm * (1.0f / 512.0f) - m * m;
        red[8] = m;
        red[9] = rsqrtf(v + 1e-5f);
    }
    __syncthreads();
    mean = red[8];
    inv  = red[9];
}

// ---------------------------------------------------------------------------
// Kernel 2: fused per-row encoder. One block (256 thr) per sorted event row.
//   h   = LN(relu(f@We1+be1)@We2+be2)
//   t   = relu(ts*Wt1+bt1)@Wt2+bt2
//   cmb = LN(([h | t | t] * amp) @ Wc + bc)
//   ctx = cmb + sinusoidal_pe(r)
// ---------------------------------------------------------------------------
__global__ __launch_bounds__(256) void encoder_kernel(
    const int* __restrict__ order, const float* __restrict__ ts_s,
    const float* __restrict__ amp_s, const float* __restrict__ feats,
    const float* __restrict__ We1, const float* __restrict__ be1,
    const float* __restrict__ We2, const float* __restrict__ be2,
    const float* __restrict__ g_ev, const float* __restrict__ b_ev,
    const float* __restrict__ Wt1, const float* __restrict__ bt1,
    const float* __restrict__ Wt2, const float* __restrict__ bt2,
    const float* __restrict__ Wc, const float* __restrict__ bc,
    const float* __restrict__ g_sr, const float* __restrict__ b_sr,
    float* __restrict__ ctx)
{
    __shared__ float sf[DIN];
    __shared__ float sh1[256];
    __shared__ float sth[128];
    __shared__ float scomb[1024];
    __shared__ float red[16];

    int r = blockIdx.x;
    int t = threadIdx.x;
    int o = order[r];
    sf[t] = feats[o * DIN + t];
    float x = ts_s[r];
    if (t < 128) sth[t] = fmaxf(fmaf(x, Wt1[t], bt1[t]), 0.0f);
    __syncthreads();

    // hidden1 = relu(sf @ We1 + be1)   [256]
    float acc = be1[t];
    #pragma unroll 4
    for (int d = 0; d < DIN; ++d) acc = fmaf(sf[d], We1[d * 256 + t], acc);
    sh1[t] = fmaxf(acc, 0.0f);
    __syncthreads();

    // h = sh1 @ We2 + be2   [512], 2 cols/thread
    float a0 = be2[t], a1 = be2[t + 256];
    #pragma unroll 4
    for (int k = 0; k < 256; ++k) {
        float hv = sh1[k];
        a0 = fmaf(hv, We2[k * 512 + t], a0);
        a1 = fmaf(hv, We2[k * 512 + t + 256], a1);
    }
    float m, inv;
    block_stats_512(a0 + a1, a0 * a0 + a1 * a1, red, m, inv);
    float ampv = amp_s[r];
    scomb[t]       = fmaf((a0 - m) * inv, g_ev[t],       b_ev[t])       * ampv;
    scomb[t + 256] = fmaf((a1 - m) * inv, g_ev[t + 256], b_ev[t + 256]) * ampv;

    // temporal layer 2: t[c] = sth @ Wt2 + bt2   [256], tiled x2
    float tv = bt2[t];
    #pragma unroll 4
    for (int k = 0; k < 128; ++k) tv = fmaf(sth[k], Wt2[k * 256 + t], tv);
    tv *= ampv;
    scomb[512 + t] = tv;
    scomb[768 + t] = tv;
    __syncthreads();

    // comb @ Wc + bc   [512], 2 cols/thread
    float c0 = bc[t], c1 = bc[t + 256];
    #pragma unroll 4
    for (int u = 0; u < 1024; ++u) {
        float uv = scomb[u];
        c0 = fmaf(uv, Wc[u * 512 + t], c0);
        c1 = fmaf(uv, Wc[u * 512 + t + 256], c1);
    }
    float m2, inv2;
    block_stats_512(c0 + c1, c0 * c0 + c1 * c1, red, m2, inv2);
    float e0 = fmaf((c0 - m2) * inv2, g_sr[t],       b_sr[t]);
    float e1 = fmaf((c1 - m2) * inv2, g_sr[t + 256], b_sr[t + 256]);

    // sinusoidal positional encoding: te[r, 2k]=sin(r*div[k]), te[r,2k+1]=cos
    const float NEG_LN1E4_OVER_H = -9.210340371976184f / 512.0f;
    float rf = (float)r;
    {
        int k0 = t >> 1;
        float ang0 = rf * expf((float)(2 * k0) * NEG_LN1E4_OVER_H);
        e0 += (t & 1) ? cosf(ang0) : sinf(ang0);
        int c = t + 256;
        int k1 = c >> 1;
        float ang1 = rf * expf((float)(2 * k1) * NEG_LN1E4_OVER_H);
        e1 += (c & 1) ? cosf(ang1) : sinf(ang1);
    }
    ctx[r * 512 + t]       = e0;
    ctx[r * 512 + t + 256] = e1;
}

// ---------------------------------------------------------------------------
// Kernel 3: Q/K/V projections, 4 rows per block (weight dword reused 4x).
// Q,V -> d_out via nontemporal stores (never re-read); Kbase -> workspace
// (cached: re-read by kexpand).
// ---------------------------------------------------------------------------
__global__ __launch_bounds__(256) void qkv_kernel(
    const float* __restrict__ ctx,
    const float* __restrict__ Wq, const float* __restrict__ bq,
    const float* __restrict__ Wk, const float* __restrict__ bk,
    const float* __restrict__ Wv, const float* __restrict__ bv,
    float* __restrict__ Qout, float* __restrict__ Kbase, float* __restrict__ Vout)
{
    __shared__ float sc[4][512];
    int r0 = blockIdx.x * 4;
    int t = threadIdx.x;
    #pragma unroll
    for (int rr = 0; rr < 4; ++rr) {
        sc[rr][t]       = ctx[(r0 + rr) * 512 + t];
        sc[rr][t + 256] = ctx[(r0 + rr) * 512 + t + 256];
    }
    __syncthreads();

    float q0[4], q1[4], k0[4], k1[4], v0[4], v1[4];
    float bq0 = bq[t], bq1 = bq[t + 256];
    float bk0 = bk[t], bk1 = bk[t + 256];
    float bv0 = bv[t], bv1 = bv[t + 256];
    #pragma unroll
    for (int rr = 0; rr < 4; ++rr) {
        q0[rr] = bq0; q1[rr] = bq1;
        k0[rr] = bk0; k1[rr] = bk1;
        v0[rr] = bv0; v1[rr] = bv1;
    }
    #pragma unroll 2
    for (int h = 0; h < 512; ++h) {
        float wq0 = Wq[h * 512 + t], wq1 = Wq[h * 512 + t + 256];
        float wk0 = Wk[h * 512 + t], wk1 = Wk[h * 512 + t + 256];
        float wv0 = Wv[h * 512 + t], wv1 = Wv[h * 512 + t + 256];
        #pragma unroll
        for (int rr = 0; rr < 4; ++rr) {
            float cv = sc[rr][h];
            q0[rr] = fmaf(cv, wq0, q0[rr]);
            q1[rr] = fmaf(cv, wq1, q1[rr]);
            k0[rr] = fmaf(cv, wk0, k0[rr]);
            k1[rr] = fmaf(cv, wk1, k1[rr]);
            v0[rr] = fmaf(cv, wv0, v0[rr]);
            v1[rr] = fmaf(cv, wv1, v1[rr]);
        }
    }
    #pragma unroll
    for (int rr = 0; rr < 4; ++rr) {
        int r = r0 + rr;
        __builtin_nontemporal_store(q0[rr], &Qout[r * 512 + t]);
        __builtin_nontemporal_store(q1[rr], &Qout[r * 512 + t + 256]);
        Kbase[r * 512 + t]       = k0[rr];
        Kbase[r * 512 + t + 256] = k1[rr];
        __builtin_nontemporal_store(v0[rr], &Vout[r * 512 + t]);
        __builtin_nontemporal_store(v1[rr], &Vout[r * 512 + t + 256]);
    }
}

// ---------------------------------------------------------------------------
// Kernel 4: K[i,j,h] = Kbase[j,h] + 0.1/(1+|i-j|).  537 MB write-bound.
//  - conn LUT in LDS (exact IEEE div once; store path is ds_read broadcast
//    + 4 v_add + nt-store)
//  - __builtin_nontemporal_store with ext_vector_type(4) float (native
//    vector -> legal operand; emits global_store_dwordx4 nt)
//  - grid.x = 8 (64 i per block): 8192 waves = 32 waves/CU (full occupancy)
//    for maximum outstanding-store depth on a pure write stream
// Fully coalesced 16B stores (1 KiB per wave-store).
// ---------------------------------------------------------------------------
__global__ __launch_bounds__(128) void kexpand_kernel(
    const float* __restrict__ Kbase, float* __restrict__ Kout)
{
    __shared__ float sconn[1024];
    int j  = blockIdx.y;            // 0..511
    int i0 = blockIdx.x * 64;       // i-chunk (8 chunks of 64)
    int t  = threadIdx.x;           // 0..127 -> 16B lane
    // LUT: 0.1/(1+d), exact IEEE division, bit-identical to per-element div.
    #pragma unroll
    for (int k = t; k < 1024; k += 128) sconn[k] = 0.1f / (float)(1 + k);
    f4 kb = ((const f4*)(Kbase + j * 512))[t];
    __syncthreads();
    f4* out = (f4*)Kout;
    size_t base = (size_t)j * 128 + t;
    #pragma unroll 8
    for (int ii = 0; ii < 64; ++ii) {
        int i = i0 + ii;
        int d = i - j; if (d < 0) d = -d;
        float conn = sconn[d];      // uniform addr -> LDS broadcast, no conflict
        f4 v = kb + conn;           // element-wise add on native vector
        __builtin_nontemporal_store(v, &out[base + (size_t)i * 65536]);
    }
}

extern "C" void kernel_launch(void* const* d_in, const int* in_sizes, int n_in,
                              void* d_out, int out_size, void* d_ws, size_t ws_size,
                              hipStream_t stream) {
    const float* timestamps = (const float*)d_in[0];
    const float* features   = (const float*)d_in[1];
    const float* amplitudes = (const float*)d_in[2];
    // d_in[3] = neuron_ids (unused by reference)
    const float* We1 = (const float*)d_in[4];
    const float* be1 = (const float*)d_in[5];
    const float* We2 = (const float*)d_in[6];
    const float* be2 = (const float*)d_in[7];
    const float* g_ev = (const float*)d_in[8];
    const float* b_ev = (const float*)d_in[9];
    const float* Wt1 = (const float*)d_in[10];
    const float* bt1 = (const float*)d_in[11];
    const float* Wt2 = (const float*)d_in[12];
    const float* bt2 = (const float*)d_in[13];
    const float* Wc  = (const float*)d_in[14];
    const float* bc  = (const float*)d_in[15];
    const float* g_sr = (const float*)d_in[16];
    const float* b_sr = (const float*)d_in[17];
    const float* Wq = (const float*)d_in[18];
    const float* bq = (const float*)d_in[19];
    const float* Wk = (const float*)d_in[20];
    const float* bk = (const float*)d_in[21];
    const float* Wv = (const float*)d_in[22];
    const float* bv = (const float*)d_in[23];

    // Output layout: Q [1,512,512] | K [512,512,512] | V [1,512,512]
    float* Qout = (float*)d_out;
    float* Kout = (float*)d_out + 262144;
    float* Vout = (float*)d_out + 262144 + 512 * 512 * 512;

    // Workspace layout (~2.1 MB)
    char* ws = (char*)d_ws;
    int*   order = (int*)ws;    ws += 512 * sizeof(int);
    float* ts_s  = (float*)ws;  ws += 512 * sizeof(float);
    float* amp_s = (float*)ws;  ws += 512 * sizeof(float);
    float* ctx   = (float*)ws;  ws += 262144 * sizeof(float);
    float* Kbase = (float*)ws;

    sort_kernel<<<1, 512, 0, stream>>>(timestamps, amplitudes, order, ts_s, amp_s);
    encoder_kernel<<<512, 256, 0, stream>>>(order, ts_s, amp_s, features,
        We1, be1, We2, be2, g_ev, b_ev, Wt1, bt1, Wt2, bt2, Wc, bc, g_sr, b_sr, ctx);
    qkv_kernel<<<128, 256, 0, stream>>>(ctx, Wq, bq, Wk, bk, Wv, bv, Qout, Kbase, Vout);
    kexpand_kernel<<<dim3(8, 512), 128, 0, stream>>>(Kbase, Kout);
}

// Round 7
// 912.446 us; speedup vs baseline: 1.0099x; 1.0099x over previous
//
#include <hip/hip_runtime.h>
#include <math.h>

#define S 512
#define DIN 256
#define H 512

// native vector type for 16B stores
typedef float f4 __attribute__((ext_vector_type(4)));

// ---------------------------------------------------------------------------
// Kernel 1: stable rank sort of 512 timestamps (matches jnp.argsort stable).
// One block, 512 threads. O(S^2) compares via LDS.
// ---------------------------------------------------------------------------
__global__ __launch_bounds__(512) void sort_kernel(
    const float* __restrict__ ts, const float* __restrict__ amp,
    int* __restrict__ order, float* __restrict__ ts_s, float* __restrict__ amp_s)
{
    __shared__ float sts[S];
    int i = threadIdx.x;
    sts[i] = ts[i];
    __syncthreads();
    float ti = sts[i];
    int rank = 0;
    for (int j = 0; j < S; ++j) {
        float tj = sts[j];
        rank += (tj < ti) || (tj == ti && j < i);
    }
    order[rank] = i;
    ts_s[rank]  = ti;
    amp_s[rank] = amp[i];
}

// Block-wide mean/rsqrt(var+eps) over 512 values held as 2 per thread (256 thr).
__device__ __forceinline__ void block_stats_512(float s, float ss, float* red,
                                                float& mean, float& inv)
{
    for (int off = 32; off > 0; off >>= 1) {
        s  += __shfl_down(s, off);
        ss += __shfl_down(ss, off);
    }
    int wid = threadIdx.x >> 6;
    if ((threadIdx.x & 63) == 0) { red[wid] = s; red[4 + wid] = ss; }
    __syncthreads();
    if (threadIdx.x == 0) {
        float Sm  = red[0] + red[1] + red[2] + red[3];
        float SSm = red[4] + red[5] + red[6] + red[7];
        float m = Sm * (1.0f / 512.0f);
        float v = SSm * (1.0f / 512.0f) - m * m;
        red[8] = m;
        red[9] = rsqrtf(v + 1e-5f);
    }
    __syncthreads();
    mean = red[8];
    inv  = red[9];
}

// ---------------------------------------------------------------------------
// Kernel 2: fused per-row encoder. One block (256 thr) per sorted event row.
//   h   = LN(relu(f@We1+be1)@We2+be2)
//   t   = relu(ts*Wt1+bt1)@Wt2+bt2
//   cmb = LN(([h | t | t] * amp) @ Wc + bc)
//   ctx = cmb + sinusoidal_pe(r)
// ---------------------------------------------------------------------------
__global__ __launch_bounds__(256) void encoder_kernel(
    const int* __restrict__ order, const float* __restrict__ ts_s,
    const float* __restrict__ amp_s, const float* __restrict__ feats,
    const float* __restrict__ We1, const float* __restrict__ be1,
    const float* __restrict__ We2, const float* __restrict__ be2,
    const float* __restrict__ g_ev, const float* __restrict__ b_ev,
    const float* __restrict__ Wt1, const float* __restrict__ bt1,
    const float* __restrict__ Wt2, const float* __restrict__ bt2,
    const float* __restrict__ Wc, const float* __restrict__ bc,
    const float* __restrict__ g_sr, const float* __restrict__ b_sr,
    float* __restrict__ ctx)
{
    __shared__ float sf[DIN];
    __shared__ float sh1[256];
    __shared__ float sth[128];
    __shared__ float scomb[1024];
    __shared__ float red[16];

    int r = blockIdx.x;
    int t = threadIdx.x;
    int o = order[r];
    sf[t] = feats[o * DIN + t];
    float x = ts_s[r];
    if (t < 128) sth[t] = fmaxf(fmaf(x, Wt1[t], bt1[t]), 0.0f);
    __syncthreads();

    // hidden1 = relu(sf @ We1 + be1)   [256]
    float acc = be1[t];
    #pragma unroll 4
    for (int d = 0; d < DIN; ++d) acc = fmaf(sf[d], We1[d * 256 + t], acc);
    sh1[t] = fmaxf(acc, 0.0f);
    __syncthreads();

    // h = sh1 @ We2 + be2   [512], 2 cols/thread
    float a0 = be2[t], a1 = be2[t + 256];
    #pragma unroll 4
    for (int k = 0; k < 256; ++k) {
        float hv = sh1[k];
        a0 = fmaf(hv, We2[k * 512 + t], a0);
        a1 = fmaf(hv, We2[k * 512 + t + 256], a1);
    }
    float m, inv;
    block_stats_512(a0 + a1, a0 * a0 + a1 * a1, red, m, inv);
    float ampv = amp_s[r];
    scomb[t]       = fmaf((a0 - m) * inv, g_ev[t],       b_ev[t])       * ampv;
    scomb[t + 256] = fmaf((a1 - m) * inv, g_ev[t + 256], b_ev[t + 256]) * ampv;

    // temporal layer 2: t[c] = sth @ Wt2 + bt2   [256], tiled x2
    float tv = bt2[t];
    #pragma unroll 4
    for (int k = 0; k < 128; ++k) tv = fmaf(sth[k], Wt2[k * 256 + t], tv);
    tv *= ampv;
    scomb[512 + t] = tv;
    scomb[768 + t] = tv;
    __syncthreads();

    // comb @ Wc + bc   [512], 2 cols/thread
    float c0 = bc[t], c1 = bc[t + 256];
    #pragma unroll 4
    for (int u = 0; u < 1024; ++u) {
        float uv = scomb[u];
        c0 = fmaf(uv, Wc[u * 512 + t], c0);
        c1 = fmaf(uv, Wc[u * 512 + t + 256], c1);
    }
    float m2, inv2;
    block_stats_512(c0 + c1, c0 * c0 + c1 * c1, red, m2, inv2);
    float e0 = fmaf((c0 - m2) * inv2, g_sr[t],       b_sr[t]);
    float e1 = fmaf((c1 - m2) * inv2, g_sr[t + 256], b_sr[t + 256]);

    // sinusoidal positional encoding: te[r, 2k]=sin(r*div[k]), te[r,2k+1]=cos
    const float NEG_LN1E4_OVER_H = -9.210340371976184f / 512.0f;
    float rf = (float)r;
    {
        int k0 = t >> 1;
        float ang0 = rf * expf((float)(2 * k0) * NEG_LN1E4_OVER_H);
        e0 += (t & 1) ? cosf(ang0) : sinf(ang0);
        int c = t + 256;
        int k1 = c >> 1;
        float ang1 = rf * expf((float)(2 * k1) * NEG_LN1E4_OVER_H);
        e1 += (c & 1) ? cosf(ang1) : sinf(ang1);
    }
    ctx[r * 512 + t]       = e0;
    ctx[r * 512 + t + 256] = e1;
}

// ---------------------------------------------------------------------------
// Kernel 3: Q/K/V projections, 4 rows per block (weight dword reused 4x).
// ---------------------------------------------------------------------------
__global__ __launch_bounds__(256) void qkv_kernel(
    const float* __restrict__ ctx,
    const float* __restrict__ Wq, const float* __restrict__ bq,
    const float* __restrict__ Wk, const float* __restrict__ bk,
    const float* __restrict__ Wv, const float* __restrict__ bv,
    float* __restrict__ Qout, float* __restrict__ Kbase, float* __restrict__ Vout)
{
    __shared__ float sc[4][512];
    int r0 = blockIdx.x * 4;
    int t = threadIdx.x;
    #pragma unroll
    for (int rr = 0; rr < 4; ++rr) {
        sc[rr][t]       = ctx[(r0 + rr) * 512 + t];
        sc[rr][t + 256] = ctx[(r0 + rr) * 512 + t + 256];
    }
    __syncthreads();

    float q0[4], q1[4], k0[4], k1[4], v0[4], v1[4];
    float bq0 = bq[t], bq1 = bq[t + 256];
    float bk0 = bk[t], bk1 = bk[t + 256];
    float bv0 = bv[t], bv1 = bv[t + 256];
    #pragma unroll
    for (int rr = 0; rr < 4; ++rr) {
        q0[rr] = bq0; q1[rr] = bq1;
        k0[rr] = bk0; k1[rr] = bk1;
        v0[rr] = bv0; v1[rr] = bv1;
    }
    #pragma unroll 2
    for (int h = 0; h < 512; ++h) {
        float wq0 = Wq[h * 512 + t], wq1 = Wq[h * 512 + t + 256];
        float wk0 = Wk[h * 512 + t], wk1 = Wk[h * 512 + t + 256];
        float wv0 = Wv[h * 512 + t], wv1 = Wv[h * 512 + t + 256];
        #pragma unroll
        for (int rr = 0; rr < 4; ++rr) {
            float cv = sc[rr][h];
            q0[rr] = fmaf(cv, wq0, q0[rr]);
            q1[rr] = fmaf(cv, wq1, q1[rr]);
            k0[rr] = fmaf(cv, wk0, k0[rr]);
            k1[rr] = fmaf(cv, wk1, k1[rr]);
            v0[rr] = fmaf(cv, wv0, v0[rr]);
            v1[rr] = fmaf(cv, wv1, v1[rr]);
        }
    }
    #pragma unroll
    for (int rr = 0; rr < 4; ++rr) {
        int r = r0 + rr;
        __builtin_nontemporal_store(q0[rr], &Qout[r * 512 + t]);
        __builtin_nontemporal_store(q1[rr], &Qout[r * 512 + t + 256]);
        Kbase[r * 512 + t]       = k0[rr];
        Kbase[r * 512 + t + 256] = k1[rr];
        __builtin_nontemporal_store(v0[rr], &Vout[r * 512 + t]);
        __builtin_nontemporal_store(v1[rr], &Vout[r * 512 + t + 256]);
    }
}

// ---------------------------------------------------------------------------
// Kernel 4: K[i,j,h] = Kbase[j,h] + 0.1/(1+|i-j|).  537 MB write-bound.
// PENDING A/B (unmeasured, 3rd submit — GPU timeouts): nt -> NORMAL stores.
// Evidence basis: harness fillBuffer dispatches hit 6.3 TB/s (79% peak)
// writing 2.1 GB with ordinary stores -> normal streaming stores provably
// reach full BW at this working-set size; Kbase re-reads are only 8 MB so
// the L2-churn rationale for nt was void. This bench attributes nt's sign.
//  - conn LUT in LDS (IEEE div off the store path)
//  - grid (8,512): 8192 waves = 32 waves/CU for store depth
// Fully coalesced 16B stores (1 KiB per wave-store).
// ---------------------------------------------------------------------------
__global__ __launch_bounds__(128) void kexpand_kernel(
    const float* __restrict__ Kbase, float* __restrict__ Kout)
{
    __shared__ float sconn[1024];
    int j  = blockIdx.y;            // 0..511
    int i0 = blockIdx.x * 64;       // i-chunk (8 chunks of 64)
    int t  = threadIdx.x;           // 0..127 -> 16B lane
    // LUT: 0.1/(1+d), exact IEEE division, bit-identical to per-element div.
    #pragma unroll
    for (int k = t; k < 1024; k += 128) sconn[k] = 0.1f / (float)(1 + k);
    f4 kb = ((const f4*)(Kbase + j * 512))[t];
    __syncthreads();
    f4* out = (f4*)Kout;
    size_t base = (size_t)j * 128 + t;
    #pragma unroll 8
    for (int ii = 0; ii < 64; ++ii) {
        int i = i0 + ii;
        int d = i - j; if (d < 0) d = -d;
        float conn = sconn[d];      // uniform addr -> LDS broadcast, no conflict
        f4 v = kb + conn;           // element-wise add on native vector
        out[base + (size_t)i * 65536] = v;   // NORMAL store (A/B vs nt)
    }
}

extern "C" void kernel_launch(void* const* d_in, const int* in_sizes, int n_in,
                              void* d_out, int out_size, void* d_ws, size_t ws_size,
                              hipStream_t stream) {
    const float* timestamps = (const float*)d_in[0];
    const float* features   = (const float*)d_in[1];
    const float* amplitudes = (const float*)d_in[2];
    // d_in[3] = neuron_ids (unused by reference)
    const float* We1 = (const float*)d_in[4];
    const float* be1 = (const float*)d_in[5];
    const float* We2 = (const float*)d_in[6];
    const float* be2 = (const float*)d_in[7];
    const float* g_ev = (const float*)d_in[8];
    const float* b_ev = (const float*)d_in[9];
    const float* Wt1 = (const float*)d_in[10];
    const float* bt1 = (const float*)d_in[11];
    const float* Wt2 = (const float*)d_in[12];
    const float* bt2 = (const float*)d_in[13];
    const float* Wc  = (const float*)d_in[14];
    const float* bc  = (const float*)d_in[15];
    const float* g_sr = (const float*)d_in[16];
    const float* b_sr = (const float*)d_in[17];
    const float* Wq = (const float*)d_in[18];
    const float* bq = (const float*)d_in[19];
    const float* Wk = (const float*)d_in[20];
    const float* bk = (const float*)d_in[21];
    const float* Wv = (const float*)d_in[22];
    const float* bv = (const float*)d_in[23];

    // Output layout: Q [1,512,512] | K [512,512,512] | V [1,512,512]
    float* Qout = (float*)d_out;
    float* Kout = (float*)d_out + 262144;
    float* Vout = (float*)d_out + 262144 + 512 * 512 * 512;

    // Workspace layout (~2.1 MB)
    char* ws = (char*)d_ws;
    int*   order = (int*)ws;    ws += 512 * sizeof(int);
    float* ts_s  = (float*)ws;  ws += 512 * sizeof(float);
    float* amp_s = (float*)ws;  ws += 512 * sizeof(float);
    float* ctx   = (float*)ws;  ws += 262144 * sizeof(float);
    float* Kbase = (float*)ws;

    sort_kernel<<<1, 512, 0, stream>>>(timestamps, amplitudes, order, ts_s, amp_s);
    encoder_kernel<<<512, 256, 0, stream>>>(order, ts_s, amp_s, features,
        We1, be1, We2, be2, g_ev, b_ev, Wt1, bt1, Wt2, bt2, Wc, bc, g_sr, b_sr, ctx);
    qkv_kernel<<<128, 256, 0, stream>>>(ctx, Wq, bq, Wk, bk, Wv, bv, Qout, Kbase, Vout);
    kexpand_kernel<<<dim3(8, 512), 128, 0, stream>>>(Kbase, Kout);
}

// Round 10
// 897.892 us; speedup vs baseline: 1.0262x; 1.0162x over previous
//
#include <hip/hip_runtime.h>
#include <math.h>

#define S 512
#define DIN 256
#define H 512

// native vector type for 16B stores
typedef float f4 __attribute__((ext_vector_type(4)));

// ---------------------------------------------------------------------------
// Kernel 1: stable rank sort of 512 timestamps (matches jnp.argsort stable).
// One block, 512 threads. O(S^2) compares via LDS.
// ---------------------------------------------------------------------------
__global__ __launch_bounds__(512) void sort_kernel(
    const float* __restrict__ ts, const float* __restrict__ amp,
    int* __restrict__ order, float* __restrict__ ts_s, float* __restrict__ amp_s)
{
    __shared__ float sts[S];
    int i = threadIdx.x;
    sts[i] = ts[i];
    __syncthreads();
    float ti = sts[i];
    int rank = 0;
    for (int j = 0; j < S; ++j) {
        float tj = sts[j];
        rank += (tj < ti) || (tj == ti && j < i);
    }
    order[rank] = i;
    ts_s[rank]  = ti;
    amp_s[rank] = amp[i];
}

// Dual-row block stats over 512 threads (1 value per row per thread).
// Butterfly within wave, 8 wave-partials in LDS, thread0 finalizes.
__device__ __forceinline__ void block_stats2_512(float v0, float v1, float* red,
    float& m0, float& i0, float& m1, float& i1)
{
    float s0 = v0, ss0 = v0 * v0, s1 = v1, ss1 = v1 * v1;
    for (int off = 32; off > 0; off >>= 1) {
        s0  += __shfl_down(s0, off);  ss0 += __shfl_down(ss0, off);
        s1  += __shfl_down(s1, off);  ss1 += __shfl_down(ss1, off);
    }
    int wid = threadIdx.x >> 6;   // 0..7
    if ((threadIdx.x & 63) == 0) {
        red[wid] = s0; red[8 + wid] = ss0; red[16 + wid] = s1; red[24 + wid] = ss1;
    }
    __syncthreads();
    if (threadIdx.x == 0) {
        float S0 = 0, SS0 = 0, S1 = 0, SS1 = 0;
        #pragma unroll
        for (int w = 0; w < 8; ++w) {
            S0 += red[w]; SS0 += red[8 + w]; S1 += red[16 + w]; SS1 += red[24 + w];
        }
        float mm0 = S0 * (1.0f / 512.0f), mm1 = S1 * (1.0f / 512.0f);
        red[32] = mm0; red[33] = rsqrtf(SS0 * (1.0f / 512.0f) - mm0 * mm0 + 1e-5f);
        red[34] = mm1; red[35] = rsqrtf(SS1 * (1.0f / 512.0f) - mm1 * mm1 + 1e-5f);
    }
    __syncthreads();
    m0 = red[32]; i0 = red[33]; m1 = red[34]; i1 = red[35];
}

// ---------------------------------------------------------------------------
// Kernel 2: fused per-row encoder — PENDING A/B (unmeasured, 3rd submit):
// 2 rows/block, 512 threads, 256 blocks. Weight loads (We1/We2/Wc/Wt2)
// shared across both rows, halving L2 weight traffic (1.43 GB -> 0.72 GB);
// 8 waves/CU retained.
// ---------------------------------------------------------------------------
__global__ __launch_bounds__(512) void encoder_kernel(
    const int* __restrict__ order, const float* __restrict__ ts_s,
    const float* __restrict__ amp_s, const float* __restrict__ feats,
    const float* __restrict__ We1, const float* __restrict__ be1,
    const float* __restrict__ We2, const float* __restrict__ be2,
    const float* __restrict__ g_ev, const float* __restrict__ b_ev,
    const float* __restrict__ Wt1, const float* __restrict__ bt1,
    const float* __restrict__ Wt2, const float* __restrict__ bt2,
    const float* __restrict__ Wc, const float* __restrict__ bc,
    const float* __restrict__ g_sr, const float* __restrict__ b_sr,
    float* __restrict__ ctx)
{
    __shared__ float sf[2][DIN];
    __shared__ float sh1[2][256];
    __shared__ float sth[2][128];
    __shared__ float scomb[2][1024];
    __shared__ float red[36];

    int r0 = blockIdx.x * 2;
    int t  = threadIdx.x;          // 0..511
    int o0 = order[r0], o1 = order[r0 + 1];
    float x0 = ts_s[r0], x1 = ts_s[r0 + 1];
    float amp0 = amp_s[r0], amp1 = amp_s[r0 + 1];

    // cooperative feature load: threads 0..255 row0, 256..511 row1
    if (t < 256) sf[0][t] = feats[o0 * DIN + t];
    else         sf[1][t - 256] = feats[o1 * DIN + (t - 256)];
    // temporal layer 1: threads 0..127 row0, 128..255 row1
    if (t < 128)               sth[0][t]       = fmaxf(fmaf(x0, Wt1[t],       bt1[t]),       0.0f);
    else if (t < 256)          sth[1][t - 128] = fmaxf(fmaf(x1, Wt1[t - 128], bt1[t - 128]), 0.0f);
    __syncthreads();

    // hidden1 = relu(sf @ We1 + be1): 512 thr -> (row = t>>8, col = t&255)
    {
        int row = t >> 8, c = t & 255;
        float acc = be1[c];
        #pragma unroll 4
        for (int d = 0; d < DIN; ++d) acc = fmaf(sf[row][d], We1[d * 256 + c], acc);
        sh1[row][c] = fmaxf(acc, 0.0f);
    }
    __syncthreads();

    // h = sh1 @ We2 + be2: thread t computes col t for BOTH rows (shared load)
    float h0 = be2[t], h1 = be2[t];
    #pragma unroll 4
    for (int k = 0; k < 256; ++k) {
        float w = We2[k * 512 + t];
        h0 = fmaf(sh1[0][k], w, h0);
        h1 = fmaf(sh1[1][k], w, h1);
    }
    float m0, inv0, m1, inv1;
    block_stats2_512(h0, h1, red, m0, inv0, m1, inv1);
    scomb[0][t] = fmaf((h0 - m0) * inv0, g_ev[t], b_ev[t]) * amp0;
    scomb[1][t] = fmaf((h1 - m1) * inv1, g_ev[t], b_ev[t]) * amp1;

    // temporal layer 2: threads 0..255 row0 col t, 256..511 row1 col t-256
    {
        int row = t >> 8, c = t & 255;
        float tv = bt2[c];
        #pragma unroll 4
        for (int k = 0; k < 128; ++k) tv = fmaf(sth[row][k], Wt2[k * 256 + c], tv);
        tv *= (row ? amp1 : amp0);
        scomb[row][512 + c] = tv;
        scomb[row][768 + c] = tv;
    }
    __syncthreads();

    // comb @ Wc + bc: thread t col t, both rows share the Wc load
    float c0 = bc[t], c1 = bc[t];
    #pragma unroll 4
    for (int u = 0; u < 1024; ++u) {
        float w = Wc[u * 512 + t];
        c0 = fmaf(scomb[0][u], w, c0);
        c1 = fmaf(scomb[1][u], w, c1);
    }
    float n0, jnv0, n1, jnv1;
    block_stats2_512(c0, c1, red, n0, jnv0, n1, jnv1);
    float e0 = fmaf((c0 - n0) * jnv0, g_sr[t], b_sr[t]);
    float e1 = fmaf((c1 - n1) * jnv1, g_sr[t], b_sr[t]);

    // sinusoidal PE: df shared across rows; 2 sincos per thread
    const float NEG_LN1E4_OVER_H = -9.210340371976184f / 512.0f;
    {
        float df = expf((float)(2 * (t >> 1)) * NEG_LN1E4_OVER_H);
        float a0 = (float)r0 * df, a1 = (float)(r0 + 1) * df;
        e0 += (t & 1) ? cosf(a0) : sinf(a0);
        e1 += (t & 1) ? cosf(a1) : sinf(a1);
    }
    ctx[r0 * 512 + t]       = e0;
    ctx[(r0 + 1) * 512 + t] = e1;
}

// ---------------------------------------------------------------------------
// Kernel 3: Q/K/V projections — PENDING A/B: column-split. Grid (128, 2) =
// 256 blocks (was 128 -> half the CUs idle). Each block: 4 rows x 256 cols,
// 12 accumulators/thread. Weight traffic unchanged (384 MB), CU util 2x.
// ---------------------------------------------------------------------------
__global__ __launch_bounds__(256) void qkv_kernel(
    const float* __restrict__ ctx,
    const float* __restrict__ Wq, const float* __restrict__ bq,
    const float* __restrict__ Wk, const float* __restrict__ bk,
    const float* __restrict__ Wv, const float* __restrict__ bv,
    float* __restrict__ Qout, float* __restrict__ Kbase, float* __restrict__ Vout)
{
    __shared__ float sc[4][512];
    int r0  = blockIdx.x * 4;
    int t   = threadIdx.x;
    int col = blockIdx.y * 256 + t;
    #pragma unroll
    for (int rr = 0; rr < 4; ++rr) {
        sc[rr][t]       = ctx[(r0 + rr) * 512 + t];
        sc[rr][t + 256] = ctx[(r0 + rr) * 512 + t + 256];
    }
    __syncthreads();

    float q[4], k[4], v[4];
    float bqc = bq[col], bkc = bk[col], bvc = bv[col];
    #pragma unroll
    for (int rr = 0; rr < 4; ++rr) { q[rr] = bqc; k[rr] = bkc; v[rr] = bvc; }

    #pragma unroll 2
    for (int h = 0; h < 512; ++h) {
        float wq = Wq[h * 512 + col];
        float wk = Wk[h * 512 + col];
        float wv = Wv[h * 512 + col];
        #pragma unroll
        for (int rr = 0; rr < 4; ++rr) {
            float cv = sc[rr][h];
            q[rr] = fmaf(cv, wq, q[rr]);
            k[rr] = fmaf(cv, wk, k[rr]);
            v[rr] = fmaf(cv, wv, v[rr]);
        }
    }
    #pragma unroll
    for (int rr = 0; rr < 4; ++rr) {
        int r = r0 + rr;
        __builtin_nontemporal_store(q[rr], &Qout[r * 512 + col]);
        Kbase[r * 512 + col] = k[rr];
        __builtin_nontemporal_store(v[rr], &Vout[r * 512 + col]);
    }
}

// ---------------------------------------------------------------------------
// Kernel 4: K[i,j,h] = Kbase[j,h] + 0.1/(1+|i-j|).  537 MB write-bound.
// MEASURED (r4 vs r7): nt=921.4, normal=912.4 -> keep NORMAL stores.
//  - conn LUT in LDS (IEEE div off the store path)
//  - grid (8,512): 8192 waves = 32 waves/CU for store depth
// Fully coalesced 16B stores (1 KiB per wave-store).
// ---------------------------------------------------------------------------
__global__ __launch_bounds__(128) void kexpand_kernel(
    const float* __restrict__ Kbase, float* __restrict__ Kout)
{
    __shared__ float sconn[1024];
    int j  = blockIdx.y;            // 0..511
    int i0 = blockIdx.x * 64;       // i-chunk (8 chunks of 64)
    int t  = threadIdx.x;           // 0..127 -> 16B lane
    #pragma unroll
    for (int k = t; k < 1024; k += 128) sconn[k] = 0.1f / (float)(1 + k);
    f4 kb = ((const f4*)(Kbase + j * 512))[t];
    __syncthreads();
    f4* out = (f4*)Kout;
    size_t base = (size_t)j * 128 + t;
    #pragma unroll 8
    for (int ii = 0; ii < 64; ++ii) {
        int i = i0 + ii;
        int d = i - j; if (d < 0) d = -d;
        float conn = sconn[d];      // uniform addr -> LDS broadcast
        f4 v = kb + conn;
        out[base + (size_t)i * 65536] = v;
    }
}

extern "C" void kernel_launch(void* const* d_in, const int* in_sizes, int n_in,
                              void* d_out, int out_size, void* d_ws, size_t ws_size,
                              hipStream_t stream) {
    const float* timestamps = (const float*)d_in[0];
    const float* features   = (const float*)d_in[1];
    const float* amplitudes = (const float*)d_in[2];
    // d_in[3] = neuron_ids (unused by reference)
    const float* We1 = (const float*)d_in[4];
    const float* be1 = (const float*)d_in[5];
    const float* We2 = (const float*)d_in[6];
    const float* be2 = (const float*)d_in[7];
    const float* g_ev = (const float*)d_in[8];
    const float* b_ev = (const float*)d_in[9];
    const float* Wt1 = (const float*)d_in[10];
    const float* bt1 = (const float*)d_in[11];
    const float* Wt2 = (const float*)d_in[12];
    const float* bt2 = (const float*)d_in[13];
    const float* Wc  = (const float*)d_in[14];
    const float* bc  = (const float*)d_in[15];
    const float* g_sr = (const float*)d_in[16];
    const float* b_sr = (const float*)d_in[17];
    const float* Wq = (const float*)d_in[18];
    const float* bq = (const float*)d_in[19];
    const float* Wk = (const float*)d_in[20];
    const float* bk = (const float*)d_in[21];
    const float* Wv = (const float*)d_in[22];
    const float* bv = (const float*)d_in[23];

    // Output layout: Q [1,512,512] | K [512,512,512] | V [1,512,512]
    float* Qout = (float*)d_out;
    float* Kout = (float*)d_out + 262144;
    float* Vout = (float*)d_out + 262144 + 512 * 512 * 512;

    // Workspace layout (~2.1 MB)
    char* ws = (char*)d_ws;
    int*   order = (int*)ws;    ws += 512 * sizeof(int);
    float* ts_s  = (float*)ws;  ws += 512 * sizeof(float);
    float* amp_s = (float*)ws;  ws += 512 * sizeof(float);
    float* ctx   = (float*)ws;  ws += 262144 * sizeof(float);
    float* Kbase = (float*)ws;

    sort_kernel<<<1, 512, 0, stream>>>(timestamps, amplitudes, order, ts_s, amp_s);
    encoder_kernel<<<256, 512, 0, stream>>>(order, ts_s, amp_s, features,
        We1, be1, We2, be2, g_ev, b_ev, Wt1, bt1, Wt2, bt2, Wc, bc, g_sr, b_sr, ctx);
    qkv_kernel<<<dim3(128, 2), 256, 0, stream>>>(ctx, Wq, bq, Wk, bk, Wv, bv, Qout, Kbase, Vout);
    kexpand_kernel<<<dim3(8, 512), 128, 0, stream>>>(Kbase, Kout);
}

// Round 11
// 892.610 us; speedup vs baseline: 1.0323x; 1.0059x over previous
//
#include <hip/hip_runtime.h>
#include <math.h>

#define S 512
#define DIN 256
#define H 512

// native vector type for 16B stores
typedef float f4 __attribute__((ext_vector_type(4)));

// ---------------------------------------------------------------------------
// Kernel 1: stable rank sort of 512 timestamps (matches jnp.argsort stable).
// One block, 512 threads. O(S^2) compares via LDS.
// ---------------------------------------------------------------------------
__global__ __launch_bounds__(512) void sort_kernel(
    const float* __restrict__ ts, const float* __restrict__ amp,
    int* __restrict__ order, float* __restrict__ ts_s, float* __restrict__ amp_s)
{
    __shared__ float sts[S];
    int i = threadIdx.x;
    sts[i] = ts[i];
    __syncthreads();
    float ti = sts[i];
    int rank = 0;
    for (int j = 0; j < S; ++j) {
        float tj = sts[j];
        rank += (tj < ti) || (tj == ti && j < i);
    }
    order[rank] = i;
    ts_s[rank]  = ti;
    amp_s[rank] = amp[i];
}

// Quad-row block stats over 512 threads (1 value per row per thread).
// Butterfly within wave, 8 wave-partials per row in LDS, thread0 finalizes.
// red needs 72 floats.
__device__ __forceinline__ void block_stats4_512(const float* v, float* red,
                                                 float* m, float* inv)
{
    float s[4], ss[4];
    #pragma unroll
    for (int rr = 0; rr < 4; ++rr) { s[rr] = v[rr]; ss[rr] = v[rr] * v[rr]; }
    for (int off = 32; off > 0; off >>= 1) {
        #pragma unroll
        for (int rr = 0; rr < 4; ++rr) {
            s[rr]  += __shfl_down(s[rr], off);
            ss[rr] += __shfl_down(ss[rr], off);
        }
    }
    int wid = threadIdx.x >> 6;   // 0..7
    if ((threadIdx.x & 63) == 0) {
        #pragma unroll
        for (int rr = 0; rr < 4; ++rr) {
            red[rr * 8 + wid]      = s[rr];
            red[32 + rr * 8 + wid] = ss[rr];
        }
    }
    __syncthreads();
    if (threadIdx.x == 0) {
        #pragma unroll
        for (int rr = 0; rr < 4; ++rr) {
            float S0 = 0.0f, SS0 = 0.0f;
            #pragma unroll
            for (int w = 0; w < 8; ++w) { S0 += red[rr * 8 + w]; SS0 += red[32 + rr * 8 + w]; }
            float mm = S0 * (1.0f / 512.0f);
            red[64 + rr] = mm;
            red[68 + rr] = rsqrtf(SS0 * (1.0f / 512.0f) - mm * mm + 1e-5f);
        }
    }
    __syncthreads();
    #pragma unroll
    for (int rr = 0; rr < 4; ++rr) { m[rr] = red[64 + rr]; inv[rr] = red[68 + rr]; }
}

// ---------------------------------------------------------------------------
// Kernel 2: fused per-row encoder — ROUND 10: 4 rows/block, 512 threads,
// 128 blocks. Weight loads (We1/We2/Wt2/Wc) shared across 4 rows:
// L2 weight traffic 717 MB (r7 2-row) -> 358 MB. LDS ~26 KB.
// Risk stated: 128 blocks = 1 block per 2 CUs; if latency-bound this
// regresses -> revert to 2-row config.
// ---------------------------------------------------------------------------
__global__ __launch_bounds__(512) void encoder_kernel(
    const int* __restrict__ order, const float* __restrict__ ts_s,
    const float* __restrict__ amp_s, const float* __restrict__ feats,
    const float* __restrict__ We1, const float* __restrict__ be1,
    const float* __restrict__ We2, const float* __restrict__ be2,
    const float* __restrict__ g_ev, const float* __restrict__ b_ev,
    const float* __restrict__ Wt1, const float* __restrict__ bt1,
    const float* __restrict__ Wt2, const float* __restrict__ bt2,
    const float* __restrict__ Wc, const float* __restrict__ bc,
    const float* __restrict__ g_sr, const float* __restrict__ b_sr,
    float* __restrict__ ctx)
{
    __shared__ float sf[4][DIN];
    __shared__ float sh1[4][256];
    __shared__ float sth[4][128];
    __shared__ float scomb[4][1024];
    __shared__ float red[72];

    int r0 = blockIdx.x * 4;
    int t  = threadIdx.x;          // 0..511

    // per-row scalars (static-indexed arrays; runtime selects done explicitly)
    float aa[4];
    aa[0] = amp_s[r0];     aa[1] = amp_s[r0 + 1];
    aa[2] = amp_s[r0 + 2]; aa[3] = amp_s[r0 + 3];
    float x0 = ts_s[r0],     x1 = ts_s[r0 + 1];
    float x2 = ts_s[r0 + 2], x3 = ts_s[r0 + 3];

    // feature load: thread (rp = t>>8, c = t&255) loads rows rp and rp+2
    {
        int rp = t >> 8, c = t & 255;
        sf[rp][c]     = feats[order[r0 + rp] * DIN + c];
        sf[rp + 2][c] = feats[order[r0 + rp + 2] * DIN + c];
    }
    // temporal layer 1: row = t>>7 (0..3), c = t&127
    {
        int rw = t >> 7, c = t & 127;
        float xv = (rw & 2) ? ((rw & 1) ? x3 : x2) : ((rw & 1) ? x1 : x0);
        sth[rw][c] = fmaxf(fmaf(xv, Wt1[c], bt1[c]), 0.0f);
    }
    __syncthreads();

    // hidden1 = relu(sf @ We1 + be1): thread covers (rp, c) and (rp+2, c),
    // sharing each We1 dword across 2 rows
    {
        int rp = t >> 8, c = t & 255;
        float a0 = be1[c], a1 = be1[c];
        #pragma unroll 4
        for (int d = 0; d < DIN; ++d) {
            float w = We1[d * 256 + c];
            a0 = fmaf(sf[rp][d],     w, a0);
            a1 = fmaf(sf[rp + 2][d], w, a1);
        }
        sh1[rp][c]     = fmaxf(a0, 0.0f);
        sh1[rp + 2][c] = fmaxf(a1, 0.0f);
    }
    __syncthreads();

    // h = sh1 @ We2 + be2: thread t = col t for ALL 4 rows (4x weight reuse)
    float h[4];
    {
        float b = be2[t];
        h[0] = b; h[1] = b; h[2] = b; h[3] = b;
    }
    #pragma unroll 4
    for (int k = 0; k < 256; ++k) {
        float w = We2[k * 512 + t];
        #pragma unroll
        for (int rr = 0; rr < 4; ++rr) h[rr] = fmaf(sh1[rr][k], w, h[rr]);
    }
    float m[4], inv[4];
    block_stats4_512(h, red, m, inv);
    #pragma unroll
    for (int rr = 0; rr < 4; ++rr)
        scomb[rr][t] = fmaf((h[rr] - m[rr]) * inv[rr], g_ev[t], b_ev[t]) * aa[rr];

    // temporal layer 2: thread covers (rp, c) and (rp+2, c), shared Wt2 dword
    {
        int rp = t >> 8, c = t & 255;
        float tv0 = bt2[c], tv1 = bt2[c];
        #pragma unroll 4
        for (int k = 0; k < 128; ++k) {
            float w = Wt2[k * 256 + c];
            tv0 = fmaf(sth[rp][k],     w, tv0);
            tv1 = fmaf(sth[rp + 2][k], w, tv1);
        }
        tv0 *= (rp ? aa[1] : aa[0]);
        tv1 *= (rp ? aa[3] : aa[2]);
        scomb[rp][512 + c]     = tv0;
        scomb[rp][768 + c]     = tv0;
        scomb[rp + 2][512 + c] = tv1;
        scomb[rp + 2][768 + c] = tv1;
    }
    __syncthreads();

    // comb @ Wc + bc: thread t = col t, 4 rows share each Wc dword
    float c4[4];
    {
        float b = bc[t];
        c4[0] = b; c4[1] = b; c4[2] = b; c4[3] = b;
    }
    #pragma unroll 4
    for (int u = 0; u < 1024; ++u) {
        float w = Wc[u * 512 + t];
        #pragma unroll
        for (int rr = 0; rr < 4; ++rr) c4[rr] = fmaf(scomb[rr][u], w, c4[rr]);
    }
    float n[4], jnv[4];
    block_stats4_512(c4, red, n, jnv);

    // LN + sinusoidal PE + store (df shared across the 4 rows)
    const float NEG_LN1E4_OVER_H = -9.210340371976184f / 512.0f;
    float df = expf((float)(2 * (t >> 1)) * NEG_LN1E4_OVER_H);
    #pragma unroll
    for (int rr = 0; rr < 4; ++rr) {
        float e = fmaf((c4[rr] - n[rr]) * jnv[rr], g_sr[t], b_sr[t]);
        float a = (float)(r0 + rr) * df;
        e += (t & 1) ? cosf(a) : sinf(a);
        ctx[(r0 + rr) * 512 + t] = e;
    }
}

// ---------------------------------------------------------------------------
// Kernel 3: Q/K/V projections — ROUND 10: 8 rows/block. Grid (64, 2) =
// 128 blocks, 256 thr, 24 acc/thread. Each weight dword reused 8x:
// L2 weight traffic 384 MB (r7) -> 192 MB. ILP 24 FMA per 3-load group
// covers latency at the reduced occupancy.
// ---------------------------------------------------------------------------
__global__ __launch_bounds__(256) void qkv_kernel(
    const float* __restrict__ ctx,
    const float* __restrict__ Wq, const float* __restrict__ bq,
    const float* __restrict__ Wk, const float* __restrict__ bk,
    const float* __restrict__ Wv, const float* __restrict__ bv,
    float* __restrict__ Qout, float* __restrict__ Kbase, float* __restrict__ Vout)
{
    __shared__ float sc[8][512];
    int r0  = blockIdx.x * 8;
    int t   = threadIdx.x;
    int col = blockIdx.y * 256 + t;
    #pragma unroll
    for (int rr = 0; rr < 8; ++rr) {
        sc[rr][t]       = ctx[(r0 + rr) * 512 + t];
        sc[rr][t + 256] = ctx[(r0 + rr) * 512 + t + 256];
    }
    __syncthreads();

    float q[8], k[8], v[8];
    float bqc = bq[col], bkc = bk[col], bvc = bv[col];
    #pragma unroll
    for (int rr = 0; rr < 8; ++rr) { q[rr] = bqc; k[rr] = bkc; v[rr] = bvc; }

    #pragma unroll 2
    for (int h = 0; h < 512; ++h) {
        float wq = Wq[h * 512 + col];
        float wk = Wk[h * 512 + col];
        float wv = Wv[h * 512 + col];
        #pragma unroll
        for (int rr = 0; rr < 8; ++rr) {
            float cv = sc[rr][h];
            q[rr] = fmaf(cv, wq, q[rr]);
            k[rr] = fmaf(cv, wk, k[rr]);
            v[rr] = fmaf(cv, wv, v[rr]);
        }
    }
    #pragma unroll
    for (int rr = 0; rr < 8; ++rr) {
        int r = r0 + rr;
        __builtin_nontemporal_store(q[rr], &Qout[r * 512 + col]);
        Kbase[r * 512 + col] = k[rr];
        __builtin_nontemporal_store(v[rr], &Vout[r * 512 + col]);
    }
}

// ---------------------------------------------------------------------------
// Kernel 4: K[i,j,h] = Kbase[j,h] + 0.1/(1+|i-j|).  537 MB write-bound.
// MEASURED (r4 vs r7): nt=921.4, normal=912.4 -> keep NORMAL stores.
//  - conn LUT in LDS (IEEE div off the store path)
//  - grid (8,512): 8192 waves = 32 waves/CU for store depth
// Fully coalesced 16B stores (1 KiB per wave-store). UNCHANGED this round.
// ---------------------------------------------------------------------------
__global__ __launch_bounds__(128) void kexpand_kernel(
    const float* __restrict__ Kbase, float* __restrict__ Kout)
{
    __shared__ float sconn[1024];
    int j  = blockIdx.y;            // 0..511
    int i0 = blockIdx.x * 64;       // i-chunk (8 chunks of 64)
    int t  = threadIdx.x;           // 0..127 -> 16B lane
    #pragma unroll
    for (int k = t; k < 1024; k += 128) sconn[k] = 0.1f / (float)(1 + k);
    f4 kb = ((const f4*)(Kbase + j * 512))[t];
    __syncthreads();
    f4* out = (f4*)Kout;
    size_t base = (size_t)j * 128 + t;
    #pragma unroll 8
    for (int ii = 0; ii < 64; ++ii) {
        int i = i0 + ii;
        int d = i - j; if (d < 0) d = -d;
        float conn = sconn[d];      // uniform addr -> LDS broadcast
        f4 v = kb + conn;
        out[base + (size_t)i * 65536] = v;
    }
}

extern "C" void kernel_launch(void* const* d_in, const int* in_sizes, int n_in,
                              void* d_out, int out_size, void* d_ws, size_t ws_size,
                              hipStream_t stream) {
    const float* timestamps = (const float*)d_in[0];
    const float* features   = (const float*)d_in[1];
    const float* amplitudes = (const float*)d_in[2];
    // d_in[3] = neuron_ids (unused by reference)
    const float* We1 = (const float*)d_in[4];
    const float* be1 = (const float*)d_in[5];
    const float* We2 = (const float*)d_in[6];
    const float* be2 = (const float*)d_in[7];
    const float* g_ev = (const float*)d_in[8];
    const float* b_ev = (const float*)d_in[9];
    const float* Wt1 = (const float*)d_in[10];
    const float* bt1 = (const float*)d_in[11];
    const float* Wt2 = (const float*)d_in[12];
    const float* bt2 = (const float*)d_in[13];
    const float* Wc  = (const float*)d_in[14];
    const float* bc  = (const float*)d_in[15];
    const float* g_sr = (const float*)d_in[16];
    const float* b_sr = (const float*)d_in[17];
    const float* Wq = (const float*)d_in[18];
    const float* bq = (const float*)d_in[19];
    const float* Wk = (const float*)d_in[20];
    const float* bk = (const float*)d_in[21];
    const float* Wv = (const float*)d_in[22];
    const float* bv = (const float*)d_in[23];

    // Output layout: Q [1,512,512] | K [512,512,512] | V [1,512,512]
    float* Qout = (float*)d_out;
    float* Kout = (float*)d_out + 262144;
    float* Vout = (float*)d_out + 262144 + 512 * 512 * 512;

    // Workspace layout (~2.1 MB)
    char* ws = (char*)d_ws;
    int*   order = (int*)ws;    ws += 512 * sizeof(int);
    float* ts_s  = (float*)ws;  ws += 512 * sizeof(float);
    float* amp_s = (float*)ws;  ws += 512 * sizeof(float);
    float* ctx   = (float*)ws;  ws += 262144 * sizeof(float);
    float* Kbase = (float*)ws;

    sort_kernel<<<1, 512, 0, stream>>>(timestamps, amplitudes, order, ts_s, amp_s);
    encoder_kernel<<<128, 512, 0, stream>>>(order, ts_s, amp_s, features,
        We1, be1, We2, be2, g_ev, b_ev, Wt1, bt1, Wt2, bt2, Wc, bc, g_sr, b_sr, ctx);
    qkv_kernel<<<dim3(64, 2), 256, 0, stream>>>(ctx, Wq, bq, Wk, bk, Wv, bv, Qout, Kbase, Vout);
    kexpand_kernel<<<dim3(8, 512), 128, 0, stream>>>(Kbase, Kout);
}